// Round 11
// baseline (47.088 us; speedup 1.0000x reference)
//
#include <hip/hip_runtime.h>
#include <hip/hip_bf16.h>

#define N_TOK 65536
#define KCB   512
#define DIM   64
#define TPB   32    // tokens per block
#define CAP   16    // per-token candidate capacity (overflow -> full rescan)

typedef __attribute__((ext_vector_type(8)))  short s16x8;
typedef __attribute__((ext_vector_type(16))) float f32x16;
typedef unsigned long long u64;

__device__ __forceinline__ unsigned bf16rne(float f) {
  unsigned u = __float_as_uint(f);
  return (u + 0x7FFFu + ((u >> 16) & 1u)) >> 16;   // round-to-nearest-even
}
__device__ __forceinline__ unsigned bf2(float lo, float hi) {
  return bf16rne(lo) | (bf16rne(hi) << 16);
}
__device__ __forceinline__ float bfback(float x) {  // RNE16(x) as f32
  return __uint_as_float(bf16rne(x) << 16);
}
// lo-residual pair: RNE16(x - RNE16(x))
__device__ __forceinline__ unsigned bf2lo(float x, float y) {
  return bf2(x - bfback(x), y - bfback(y));
}
// Monotone f32->u32: unsigned compare == float compare (total order).
__device__ __forceinline__ unsigned mono(float f) {
  unsigned u = __float_as_uint(f);
  return u ^ ((unsigned)((int)u >> 31) | 0x80000000u);
}
__device__ __forceinline__ u64 u64min(u64 a, u64 b) { return a < b ? a : b; }

// Exact f32 score of row k for an 8-lane group's token (INLINE — no ABI).
// erow points into GLOBAL emb (L2-hot). 3x shfl_xor completes the 64-dot.
__device__ __forceinline__ u64 group_score8(
    const float* __restrict__ cb, const float* __restrict__ erow,
    const float* __restrict__ csql, int k, int sub) {
  const float4* c4 = reinterpret_cast<const float4*>(cb + (size_t)k * DIM + sub * 8);
  const float4* e4 = reinterpret_cast<const float4*>(erow);
  const float4 c0 = c4[0], c1 = c4[1], e0 = e4[0], e1 = e4[1];
  float s0 = 0.f, s1 = 0.f;
  s0 = fmaf(c0.x, e0.x, s0); s1 = fmaf(c0.y, e0.y, s1);
  s0 = fmaf(c0.z, e0.z, s0); s1 = fmaf(c0.w, e0.w, s1);
  s0 = fmaf(c1.x, e1.x, s0); s1 = fmaf(c1.y, e1.y, s1);
  s0 = fmaf(c1.z, e1.z, s0); s1 = fmaf(c1.w, e1.w, s1);
  float p = s0 + s1;
  p += __shfl_xor(p, 1);
  p += __shfl_xor(p, 2);
  p += __shfl_xor(p, 4);
  const float S = fmaf(-2.f, p, csql[k]);
  return ((u64)mono(S) << 32) | (unsigned)k;
}

// Prep: codebook -> fragment-major HI and LO bf16 sets + csq.
// hi = RNE16(c); lo = RNE16(c - hi). frag[i] hi, frag[4096+i] lo.
__global__ __launch_bounds__(256) void vq_prep_kernel(
    const float* __restrict__ cb, uint4* __restrict__ cb_frag,
    float* __restrict__ csqg) {
  const int gid = blockIdx.x * 256 + threadIdx.x;
  if (gid < 4096) {                       // 16 RT x 4 s x 64 lanes
    const int f = gid >> 6, lane = gid & 63;
    const int RT = f >> 2, s = f & 3;
    const int row = RT * 32 + (lane & 31);
    const float4* src =
        reinterpret_cast<const float4*>(cb + (size_t)row * DIM + s * 16 + (lane >> 5) * 8);
    const float4 a = src[0], b = src[1];
    cb_frag[gid] = make_uint4(bf2(a.x, a.y), bf2(a.z, a.w), bf2(b.x, b.y), bf2(b.z, b.w));
    cb_frag[4096 + gid] =
        make_uint4(bf2lo(a.x, a.y), bf2lo(a.z, a.w), bf2lo(b.x, b.y), bf2lo(b.z, b.w));
  } else if (gid < 4096 + KCB) {
    const int k = gid - 4096;
    const float4* r4 = reinterpret_cast<const float4*>(cb + (size_t)k * DIM);
    float s = 0.f;
#pragma unroll
    for (int i = 0; i < 16; ++i) {
      float4 c = r4[i];
      s = fmaf(c.x, c.x, s); s = fmaf(c.y, c.y, s);
      s = fmaf(c.z, c.z, s); s = fmaf(c.w, c.w, s);
    }
    csqg[k] = s;
  }
}

// Split-precision certified argmin + fused gather.
// dot = hiA*hiB + hiA*loB + loA*hiB in one f32 MFMA accumulator:
// |S_approx - S_f32| <= 1e-4*||e|| + 1e-5 (with >2x slack). Pass A tracks
// (m1,k1,m2); margin-resolved tokens are final with NO recompute. Only
// unresolved (~0.4%) trigger pass B tiles + phase C exact rescore.
__global__ __launch_bounds__(256, 5) void vq_argmin_kernel(
    const float* __restrict__ cb,
    const float* __restrict__ emb,
    const uint4* __restrict__ cb_frag,
    const float* __restrict__ csqg,
    float* __restrict__ out) {
  __shared__ char  etile[TPB * 128];     // 4 KB swizzled bf16 hi tokens
  __shared__ char  etilo[TPB * 128];     // 4 KB swizzled bf16 lo tokens
  __shared__ float csq_l[KCB];           // 2 KB
  __shared__ float esq_p[256];           // 1 KB (8 partials per token)
  __shared__ float mA[4][TPB];           // per-wave m1
  __shared__ float mB[4][TPB];           // per-wave m2
  __shared__ int   kA[4][TPB];           // per-wave k1
  __shared__ int   cnt[TPB];
  __shared__ short list[TPB][CAP];
  __shared__ int   sel[TPB];
  __shared__ int   needR[TPB];

  const int tid  = threadIdx.x;
  const int lane = tid & 63;
  const int w    = tid >> 6;
  const int col  = lane & 31;            // token within block
  const int half = lane >> 5;
  const int blk  = blockIdx.x;

  if (tid < TPB) cnt[tid] = 0;

  // ---- stage 32 tokens: 8 f32/thread -> hi + lo bf16 swizzled LDS ----
  {
    const float4* ep4 = reinterpret_cast<const float4*>(emb + (size_t)blk * TPB * DIM);
    const float4 v0 = ep4[tid * 2 + 0], v1 = ep4[tid * 2 + 1];
    float ss = 0.f;
    ss = fmaf(v0.x, v0.x, ss); ss = fmaf(v0.y, v0.y, ss);
    ss = fmaf(v0.z, v0.z, ss); ss = fmaf(v0.w, v0.w, ss);
    ss = fmaf(v1.x, v1.x, ss); ss = fmaf(v1.y, v1.y, ss);
    ss = fmaf(v1.z, v1.z, ss); ss = fmaf(v1.w, v1.w, ss);
    esq_p[tid] = ss;
    const int tok = tid >> 3, c0 = tid & 7;        // 16B bf16 chunk c0
    const int a0 = tok * 128 + ((16 * c0) ^ ((tok & 7) << 4));
    *reinterpret_cast<uint4*>(etile + a0) =
        make_uint4(bf2(v0.x, v0.y), bf2(v0.z, v0.w), bf2(v1.x, v1.y), bf2(v1.z, v1.w));
    *reinterpret_cast<uint4*>(etilo + a0) =
        make_uint4(bf2lo(v0.x, v0.y), bf2lo(v0.z, v0.w), bf2lo(v1.x, v1.y), bf2lo(v1.z, v1.w));
  }
  if (tid < 128)
    reinterpret_cast<float4*>(csq_l)[tid] = reinterpret_cast<const float4*>(csqg)[tid];
  __syncthreads();                                          // barrier 1

  // ---- B-fragment preload: hi + lo (8 ds_read_b128 per lane) ----
  s16x8 Bh[4], Bl[4];
#pragma unroll
  for (int s = 0; s < 4; ++s) {
    const int c = 2 * s + half;
    const int a = col * 128 + ((16 * c) ^ ((col & 7) << 4));
    Bh[s] = *reinterpret_cast<const s16x8*>(etile + a);
    Bl[s] = *reinterpret_cast<const s16x8*>(etilo + a);
  }

  const int rowbase = w * 128;
  const s16x8* frag = reinterpret_cast<const s16x8*>(cb_frag);
  const s16x8* fragLo = frag + 4096;

  // ---- Pass A: split MFMA -> (m1,k1,m2) + per-tile gmin ----
  float gmin[4];
  float m1 = 3.4e38f, m2 = 3.4e38f;
  int k1 = 0;
#pragma unroll
  for (int rt = 0; rt < 4; ++rt) {
    const int fb = ((w * 4 + rt) * 4) * 64 + lane;
    s16x8 Ah[4];
#pragma unroll
    for (int s = 0; s < 4; ++s) Ah[s] = frag[fb + s * 64];
    f32x16 a0 = {};
#pragma unroll
    for (int s = 0; s < 4; ++s)
      a0 = __builtin_amdgcn_mfma_f32_32x32x16_bf16(Ah[s], Bh[s], a0, 0, 0, 0);
#pragma unroll
    for (int s = 0; s < 4; ++s)
      a0 = __builtin_amdgcn_mfma_f32_32x32x16_bf16(Ah[s], Bl[s], a0, 0, 0, 0);
#pragma unroll
    for (int s = 0; s < 4; ++s) {
      const s16x8 Al = fragLo[fb + s * 64];
      a0 = __builtin_amdgcn_mfma_f32_32x32x16_bf16(Al, Bh[s], a0, 0, 0, 0);
    }
    const int rb = rowbase + rt * 32 + 4 * half;
    float m1t = 3.4e38f, m2t = 3.4e38f;
    int k1t = rb;
#pragma unroll
    for (int gq = 0; gq < 4; ++gq) {
      const float4 cs = *reinterpret_cast<const float4*>(&csq_l[rb + 8 * gq]);
#pragma unroll
      for (int e = 0; e < 4; ++e) {
        const float c = (e == 0) ? cs.x : (e == 1) ? cs.y : (e == 2) ? cs.z : cs.w;
        const float S = fmaf(-2.f, a0[gq * 4 + e], c);
        const float tmx = fmaxf(m1t, S);
        m2t = fminf(m2t, tmx);
        const bool lt = S < m1t;               // strict: lowest k kept
        k1t = lt ? (rb + 8 * gq + e) : k1t;
        m1t = fminf(m1t, S);
      }
    }
    gmin[rt] = m1t;
    const float tmx = fmaxf(m1, m1t);
    m2 = fminf(fminf(m2, m2t), tmx);
    if (m1t < m1) k1 = k1t;                    // tiles ascend in k
    m1 = fminf(m1, m1t);
  }
  // wave halves merge (rows interleave: tie-break needs k compare)
  {
    const float m1o = __shfl_xor(m1, 32);
    const float m2o = __shfl_xor(m2, 32);
    const int k1o = __shfl_xor(k1, 32);
    const float tmx = fmaxf(m1, m1o);
    m2 = fminf(fminf(m2, m2o), tmx);
    const bool better = (m1o < m1) || (m1o == m1 && k1o < k1);
    k1 = better ? k1o : k1;
    m1 = fminf(m1, m1o);
  }
  if (lane < 32) { mA[w][col] = m1; mB[w][col] = m2; kA[w][col] = k1; }
  __syncthreads();                                          // barrier 2

  // ---- block merge + margin certification (redundant per lane) ----
  float thr;
  {
    float bm1 = mA[0][col], bm2 = mB[0][col];
    int bk = kA[0][col];
#pragma unroll
    for (int w2 = 1; w2 < 4; ++w2) {
      const float om1 = mA[w2][col], om2 = mB[w2][col];
      const int ok = kA[w2][col];
      const float tmx = fmaxf(bm1, om1);
      bm2 = fminf(fminf(bm2, om2), tmx);
      if (om1 < bm1) bk = ok;                  // disjoint ascending k ranges
      bm1 = fminf(bm1, om1);
    }
    const float esq = ((esq_p[col * 8 + 0] + esq_p[col * 8 + 1]) +
                       (esq_p[col * 8 + 2] + esq_p[col * 8 + 3])) +
                      ((esq_p[col * 8 + 4] + esq_p[col * 8 + 5]) +
                       (esq_p[col * 8 + 6] + esq_p[col * 8 + 7]));
    const float marg = 2e-4f * sqrtf(esq) + 2e-5f;   // 2B, >2x slack
    const bool res = (bm2 - bm1) > marg;
    thr = res ? -3.4e38f : (bm1 + marg);
    if (tid < TPB) {
      needR[tid] = res ? 0 : 1;
      if (res) {
        sel[tid] = bk;
        out[(size_t)2 * N_TOK * DIM + blk * TPB + tid] = (float)bk;
      }
    }
  }

  // ---- Pass B (rare): bit-identical recompute of surviving tiles ----
#pragma unroll
  for (int rt = 0; rt < 4; ++rt) {
    if (!__any(gmin[rt] <= thr)) continue;
    const int fb = ((w * 4 + rt) * 4) * 64 + lane;
    s16x8 Ah[4];
#pragma unroll
    for (int s = 0; s < 4; ++s) Ah[s] = frag[fb + s * 64];
    f32x16 a0 = {};
#pragma unroll
    for (int s = 0; s < 4; ++s)
      a0 = __builtin_amdgcn_mfma_f32_32x32x16_bf16(Ah[s], Bh[s], a0, 0, 0, 0);
#pragma unroll
    for (int s = 0; s < 4; ++s)
      a0 = __builtin_amdgcn_mfma_f32_32x32x16_bf16(Ah[s], Bl[s], a0, 0, 0, 0);
#pragma unroll
    for (int s = 0; s < 4; ++s) {
      const s16x8 Al = fragLo[fb + s * 64];
      a0 = __builtin_amdgcn_mfma_f32_32x32x16_bf16(Al, Bh[s], a0, 0, 0, 0);
    }
    const int rb = rowbase + rt * 32 + 4 * half;
#pragma unroll
    for (int gq = 0; gq < 4; ++gq) {
      const float4 cs = *reinterpret_cast<const float4*>(&csq_l[rb + 8 * gq]);
#pragma unroll
      for (int e = 0; e < 4; ++e) {
        const float c = (e == 0) ? cs.x : (e == 1) ? cs.y : (e == 2) ? cs.z : cs.w;
        if (fmaf(-2.f, a0[gq * 4 + e], c) <= thr) {
          const int p = atomicAdd(&cnt[col], 1);
          if (p < CAP) list[col][p] = (short)(rb + 8 * gq + e);
        }
      }
    }
  }
  __syncthreads();                                          // barrier 3

  // ---- Phase C (rare): 8 lanes per unresolved token, exact f32 rescore ----
  {
    const int t = tid >> 3, sub = tid & 7;
    if (needR[t]) {
      const int nc = cnt[t];
      const float* erow = emb + (size_t)(blk * TPB + t) * DIM + sub * 8;
      u64 bb = ~0ull;
      if (nc <= CAP) {
        for (int i = 0; i < nc; ++i)
          bb = u64min(bb, group_score8(cb, erow, csq_l, list[t][i], sub));
      } else {
        for (int k = 0; k < KCB; ++k)
          bb = u64min(bb, group_score8(cb, erow, csq_l, k, sub));
      }
      if (sub == 0) {
        const int idx = (int)(unsigned)(bb & 0xFFFFFFFFull);
        sel[t] = idx;
        out[(size_t)2 * N_TOK * DIM + blk * TPB + t] = (float)idx;
      }
    }
  }
  __syncthreads();                                          // barrier 4

  // ---- Phase D: fused gather-write of both quantized sections ----
  {
    const float4* cb4 = reinterpret_cast<const float4*>(cb);
    float4* out4 = reinterpret_cast<float4*>(out);
#pragma unroll
    for (int mm = 0; mm < 2; ++mm) {
      const int i = tid + 256 * mm;
      const int t = i >> 4, j = i & 15;
      const float4 v = cb4[sel[t] * (DIM / 4) + j];
      const size_t g = (size_t)(blk * TPB + t) * (DIM / 4) + j;
      out4[g] = v;
      out4[(size_t)N_TOK * (DIM / 4) + g] = v;
    }
  }
}

extern "C" void kernel_launch(void* const* d_in, const int* in_sizes, int n_in,
                              void* d_out, int out_size, void* d_ws, size_t ws_size,
                              hipStream_t stream) {
  const float* cb  = (const float*)d_in[0];   // (512, 64) f32
  const float* emb = (const float*)d_in[1];   // (65536, 1, 64) f32
  float* out = (float*)d_out;
  uint4* cb_frag = (uint4*)d_ws;                            // 128 KB hi+lo fragments
  float* csqg = (float*)((char*)d_ws + 131072);             // 2 KB csq

  vq_prep_kernel<<<18, 256, 0, stream>>>(cb, cb_frag, csqg);
  vq_argmin_kernel<<<N_TOK / TPB, 256, 0, stream>>>(cb, emb, cb_frag, csqg, out);
}